// Round 4
// baseline (151.696 us; speedup 1.0000x reference)
//
#include <hip/hip_runtime.h>
#include <hip/hip_bf16.h>

#define IN_C 512
#define HID_C 128
#define OUT_C 16

typedef float f32x4 __attribute__((ext_vector_type(4)));

// ---------------------------------------------------------------------------
// K1: folded weights + bias const + zero deg.
//   Wc[o][k] = sum_h W2[o][h] * W1[h][k]   (16 x 512)
//   cconst[o] = b2[o] + sum_h b1[h] * W2[o][h]
//   blocks 0..31: Wc; block 32: cconst; blocks 33+: deg[.] = 0
// ---------------------------------------------------------------------------
__global__ void prep_kernel(const float* __restrict__ W1, const float* __restrict__ b1,
                            const float* __restrict__ W2, const float* __restrict__ b2,
                            float* __restrict__ Wc, float* __restrict__ cconst,
                            int* __restrict__ deg, int N) {
    if (blockIdx.x < 32) {
        int idx = blockIdx.x * 256 + threadIdx.x;   // 0 .. 8191
        int o = idx >> 9;                            // /512
        int k = idx & 511;
        float s = 0.f;
#pragma unroll 8
        for (int h = 0; h < HID_C; ++h)
            s = fmaf(W2[o * HID_C + h], W1[h * IN_C + k], s);
        Wc[o * IN_C + k] = s;
    } else if (blockIdx.x == 32) {
        if (threadIdx.x < OUT_C) {
            int o = threadIdx.x;
            float s = b2[o];
            for (int h = 0; h < HID_C; ++h)
                s = fmaf(b1[h], W2[o * HID_C + h], s);
            cconst[o] = s;
        }
    } else {
        int n = (blockIdx.x - 33) * 256 + threadIdx.x;
        if (n < N) deg[n] = 0;
    }
}

// K2: deg[c]++ per edge (int atomics)
__global__ void deg_kernel(const int* __restrict__ ei, int* __restrict__ deg, int E) {
    int e = blockIdx.x * 256 + threadIdx.x;
    if (e < E) atomicAdd(&deg[ei[E + e]], 1);
}

// K3: per-block sums of deg
__global__ void scan1_kernel(const int* __restrict__ deg, int* __restrict__ bsum, int N) {
    __shared__ int red[256];
    int tid = threadIdx.x;
    int n = blockIdx.x * 256 + tid;
    red[tid] = (n < N) ? deg[n] : 0;
    __syncthreads();
    for (int s = 128; s > 0; s >>= 1) {
        if (tid < s) red[tid] += red[tid + s];
        __syncthreads();
    }
    if (tid == 0) bsum[blockIdx.x] = red[0];
}

// K4: off[n] = exclusive-prefix(deg)[n]; cursor[n]=off[n]; dsq[n]=sqrt(deg[n])
__global__ void scan2_kernel(const int* __restrict__ deg, const int* __restrict__ bsum,
                             int* __restrict__ off, int* __restrict__ cursor,
                             float* __restrict__ dsq, int N, int NB) {
    __shared__ int red[256];
    __shared__ int lds[256];
    __shared__ int base_s;
    const int b = blockIdx.x, tid = threadIdx.x;
    // base = sum of bsum[0..b-1], block-parallel reduce
    red[tid] = (tid < b && tid < NB) ? bsum[tid] : 0;
    __syncthreads();
    for (int s = 128; s > 0; s >>= 1) {
        if (tid < s) red[tid] += red[tid + s];
        __syncthreads();
    }
    if (tid == 0) base_s = red[0];
    // intra-block inclusive scan (Hillis-Steele)
    int n = b * 256 + tid;
    int v = (n < N) ? deg[n] : 0;
    lds[tid] = v;
    __syncthreads();
    for (int s = 1; s < 256; s <<= 1) {
        int t = (tid >= s) ? lds[tid - s] : 0;
        __syncthreads();
        lds[tid] += t;
        __syncthreads();
    }
    if (n < N) {
        int o = base_s + lds[tid] - v;   // exclusive
        off[n] = o;
        cursor[n] = o;
        dsq[n] = sqrtf((float)v);
    }
}

// K5: CSR bucketing: esrc[cursor[c]++] = r
__global__ void bucket_kernel(const int* __restrict__ ei, int* __restrict__ cursor,
                              int* __restrict__ esrc, int E) {
    int e = blockIdx.x * 256 + threadIdx.x;
    if (e < E) {
        int r = ei[e];
        int c = ei[E + e];
        int p = atomicAdd(&cursor[c], 1);
        esrc[p] = r;
    }
}

// ---------------------------------------------------------------------------
// K6: h2 = x @ Wc^T   [N,16].  One wave per row; Wc in 128 VGPRs.
// ---------------------------------------------------------------------------
__global__ __launch_bounds__(256, 2) void h2_kernel(const float* __restrict__ x,
                                                    const float* __restrict__ Wc,
                                                    float* __restrict__ h2, int N) {
    const int lane = threadIdx.x & 63;
    const int gw = (blockIdx.x * 256 + threadIdx.x) >> 6;
    const int nw = (gridDim.x * 256) >> 6;

    f32x4 w0[16], w1[16];
#pragma unroll
    for (int o = 0; o < 16; ++o) {
        w0[o] = *(const f32x4*)(Wc + o * IN_C + 4 * lane);
        w1[o] = *(const f32x4*)(Wc + o * IN_C + 256 + 4 * lane);
    }

    for (int r = gw; r < N; r += nw) {
        const f32x4 a0 = *(const f32x4*)(x + (size_t)r * IN_C + 4 * lane);
        const f32x4 a1 = *(const f32x4*)(x + (size_t)r * IN_C + 256 + 4 * lane);
        float p[16];
#pragma unroll
        for (int o = 0; o < 16; ++o) {
            float s = a0.x * w0[o].x;
            s = fmaf(a0.y, w0[o].y, s);
            s = fmaf(a0.z, w0[o].z, s);
            s = fmaf(a0.w, w0[o].w, s);
            s = fmaf(a1.x, w1[o].x, s);
            s = fmaf(a1.y, w1[o].y, s);
            s = fmaf(a1.z, w1[o].z, s);
            s = fmaf(a1.w, w1[o].w, s);
            p[o] = s;
        }
#define RSTEP(MASK, HALF)                                            \
        {                                                            \
            const bool hi = (lane & MASK) != 0;                      \
            _Pragma("unroll")                                        \
            for (int i = 0; i < HALF; ++i) {                         \
                float send = hi ? p[i] : p[i + HALF];                \
                float recv = __shfl_xor(send, MASK, 64);             \
                float keep = hi ? p[i + HALF] : p[i];                \
                p[i] = keep + recv;                                  \
            }                                                        \
        }
        RSTEP(1, 8)
        RSTEP(2, 4)
        RSTEP(4, 2)
        RSTEP(8, 1)
#undef RSTEP
        float v = p[0];
        v += __shfl_xor(v, 16, 64);
        v += __shfl_xor(v, 32, 64);
        if (lane < 16) {
            int o = ((lane & 1) << 3) | ((lane & 2) << 1) | ((lane & 4) >> 1) | ((lane & 8) >> 3);
            h2[(size_t)r * 16 + o] = v;
        }
    }
}

// ---------------------------------------------------------------------------
// K7: gather: out[c][o] = cconst[o] + dsq[c] * sum_{e in bucket(c)} dsq[r]*h2[r][o]
// 16 lanes per node; esrc/dsq loads broadcast, h2 load is one 64B line.
// ---------------------------------------------------------------------------
__global__ __launch_bounds__(256) void gather_kernel(const int* __restrict__ off,
                                                     const int* __restrict__ deg,
                                                     const int* __restrict__ esrc,
                                                     const float* __restrict__ dsq,
                                                     const float* __restrict__ h2,
                                                     const float* __restrict__ cconst,
                                                     float* __restrict__ out, int N) {
    int g = blockIdx.x * 16 + (threadIdx.x >> 4);
    int o = threadIdx.x & 15;
    if (g >= N) return;
    const int start = off[g];
    const int cnt = deg[g];
    float acc = 0.f;
#pragma unroll 4
    for (int j = 0; j < cnt; ++j) {
        int r = esrc[start + j];
        acc = fmaf(dsq[r], h2[r * 16 + o], acc);
    }
    out[g * 16 + o] = fmaf(dsq[g], acc, cconst[o]);
}

// ---------------------------------------------------------------------------
extern "C" void kernel_launch(void* const* d_in, const int* in_sizes, int n_in,
                              void* d_out, int out_size, void* d_ws, size_t ws_size,
                              hipStream_t stream) {
    const float* x  = (const float*)d_in[0];
    const int*   ei = (const int*)d_in[1];
    const float* W1 = (const float*)d_in[2];
    const float* b1 = (const float*)d_in[3];
    const float* W2 = (const float*)d_in[4];
    const float* b2 = (const float*)d_in[5];
    float* out = (float*)d_out;

    const int N = in_sizes[0] / IN_C;
    const int E = in_sizes[1] / 2;
    const int NB = (N + 255) / 256;

    // workspace layout (4-byte units):
    // Wc[8192] | cconst[16] | dsq[N] | h2[16N] | deg[N] | off[N] | cursor[N] | bsum[NB] | esrc[E]
    float* ws     = (float*)d_ws;
    float* Wc     = ws;
    float* cconst = ws + 16 * IN_C;
    float* dsq    = cconst + 16;
    float* h2     = dsq + N;
    int*   deg    = (int*)(h2 + (size_t)16 * N);
    int*   off    = deg + N;
    int*   cursor = off + N;
    int*   bsum   = cursor + N;
    int*   esrc   = bsum + NB;
    // total ≈ (8208 + 20N + NB + E) * 4B ≈ 7.3 MB

    hipLaunchKernelGGL(prep_kernel, dim3(33 + NB), dim3(256), 0, stream,
                       W1, b1, W2, b2, Wc, cconst, deg, N);
    hipLaunchKernelGGL(deg_kernel, dim3((E + 255) / 256), dim3(256), 0, stream, ei, deg, E);
    hipLaunchKernelGGL(scan1_kernel, dim3(NB), dim3(256), 0, stream, deg, bsum, N);
    hipLaunchKernelGGL(scan2_kernel, dim3(NB), dim3(256), 0, stream, deg, bsum, off, cursor, dsq, N, NB);
    hipLaunchKernelGGL(bucket_kernel, dim3((E + 255) / 256), dim3(256), 0, stream, ei, cursor, esrc, E);
    hipLaunchKernelGGL(h2_kernel, dim3(512), dim3(256), 0, stream, x, Wc, h2, N);
    hipLaunchKernelGGL(gather_kernel, dim3((N + 15) / 16), dim3(256), 0, stream,
                       off, deg, esrc, dsq, h2, cconst, out, N);
}